// Round 1
// baseline (659.543 us; speedup 1.0000x reference)
//
#include <hip/hip_runtime.h>

// Problem constants
#define B_  64
#define S_  512
#define D_  768
#define H_  768
#define C_  5
#define M_  (B_ * S_)        // 32768 rows

// GEMM tiling
#define BM 128
#define BN 128
#define BK 8
#define LDSS 132             // padded LDS row stride in floats (mult of 4 for float4 align)

// -------------------------------------------------------------------------
// Kernel 1: initialize pot[b][t][c] = b2[c] + (t==0)*left[c] + (t==S-1)*right[c]
// pot lives directly in its final d_out location; GEMM atomics accumulate on top.
// -------------------------------------------------------------------------
__global__ __launch_bounds__(256) void init_pot_kernel(
    const float* __restrict__ b2, const float* __restrict__ lb,
    const float* __restrict__ rb, float* __restrict__ pot)
{
    const int idx = blockIdx.x * 256 + threadIdx.x;
    if (idx < M_ * C_) {
        const int c = idx % C_;
        const int t = (idx / C_) & (S_ - 1);
        float v = b2[c];
        if (t == 0)      v += lb[c];
        if (t == S_ - 1) v += rb[c];
        pot[idx] = v;
    }
}

// -------------------------------------------------------------------------
// Kernel 2: fused  h = relu(X @ W1 + b1);  pot += h @ W2   (partial per n-tile)
// fp32 vector-ALU GEMM, 128x128 block tile, 8x8 per thread (2x2 quadrants of 4).
// -------------------------------------------------------------------------
__global__ __launch_bounds__(256) void gemm_relu_pot_kernel(
    const float* __restrict__ X,    // [M_, D_]
    const float* __restrict__ W1,   // [D_, H_]
    const float* __restrict__ b1,   // [H_]
    const float* __restrict__ W2,   // [H_, C_]
    float* __restrict__ pot)        // [M_, C_]  (pre-initialized)
{
    __shared__ float As[BK * LDSS];       // transposed A tile: As[k][m]
    __shared__ float Bs[BK * LDSS];       // B tile: Bs[k][n]
    __shared__ float w2s[BN][C_];         // W2 tile for this block's n-range

    const int tid = threadIdx.x;
    const int tx  = tid & 15;             // n direction (16)
    const int ty  = tid >> 4;             // m direction (16)
    const int m0  = blockIdx.y * BM;
    const int n0  = blockIdx.x * BN;

    // stage W2 tile
    for (int idx = tid; idx < BN * C_; idx += 256)
        w2s[idx / C_][idx % C_] = W2[(n0 + idx / C_) * C_ + idx % C_];

    float acc[2][2][4][4];
    #pragma unroll
    for (int a = 0; a < 2; ++a)
        #pragma unroll
        for (int b = 0; b < 2; ++b)
            #pragma unroll
            for (int i = 0; i < 4; ++i)
                #pragma unroll
                for (int j = 0; j < 4; ++j)
                    acc[a][b][i][j] = 0.f;

    // A staging: 128 rows x 8 k, one float4 per thread (2 threads/row)
    const int arow = tid >> 1;
    const int aq   = tid & 1;
    // B staging: 8 k x 128 n, one float4 per thread (32 threads/row)
    const int brow = tid >> 5;
    const int bq   = tid & 31;

    const float* Aptr = X  + (m0 + arow) * D_ + aq * 4;
    const float* Bptr = W1 + brow * H_ + n0 + bq * 4;

    for (int kt = 0; kt < D_; kt += BK) {
        const float4 av = *(const float4*)Aptr;
        const float4 bv = *(const float4*)Bptr;
        __syncthreads();
        // transpose-store A (scalar; 2-way bank aliasing = free)
        As[(aq * 4 + 0) * LDSS + arow] = av.x;
        As[(aq * 4 + 1) * LDSS + arow] = av.y;
        As[(aq * 4 + 2) * LDSS + arow] = av.z;
        As[(aq * 4 + 3) * LDSS + arow] = av.w;
        *(float4*)&Bs[brow * LDSS + bq * 4] = bv;
        __syncthreads();

        #pragma unroll
        for (int k = 0; k < BK; ++k) {
            const float4 a0 = *(const float4*)&As[k * LDSS + (ty << 2)];
            const float4 a1 = *(const float4*)&As[k * LDSS + 64 + (ty << 2)];
            const float4 bb0 = *(const float4*)&Bs[k * LDSS + (tx << 2)];
            const float4 bb1 = *(const float4*)&Bs[k * LDSS + 64 + (tx << 2)];
            const float ar[2][4] = {{a0.x, a0.y, a0.z, a0.w}, {a1.x, a1.y, a1.z, a1.w}};
            const float br[2][4] = {{bb0.x, bb0.y, bb0.z, bb0.w}, {bb1.x, bb1.y, bb1.z, bb1.w}};
            #pragma unroll
            for (int ri = 0; ri < 2; ++ri)
                #pragma unroll
                for (int i = 0; i < 4; ++i)
                    #pragma unroll
                    for (int rj = 0; rj < 2; ++rj)
                        #pragma unroll
                        for (int j = 0; j < 4; ++j)
                            acc[ri][rj][i][j] = fmaf(ar[ri][i], br[rj][j], acc[ri][rj][i][j]);
        }
        Aptr += BK;
        Bptr += BK * H_;
    }

    // Epilogue: bias + relu, then partial pot = h @ W2 over this block's 128 cols.
    // ps[ri][i][c] accumulates over this thread's 8 columns; shuffle-reduce over tx.
    float ps[2][4][C_];
    #pragma unroll
    for (int ri = 0; ri < 2; ++ri)
        #pragma unroll
        for (int i = 0; i < 4; ++i)
            #pragma unroll
            for (int cc = 0; cc < C_; ++cc)
                ps[ri][i][cc] = 0.f;

    #pragma unroll
    for (int rj = 0; rj < 2; ++rj) {
        #pragma unroll
        for (int j = 0; j < 4; ++j) {
            const int nl = rj * 64 + (tx << 2) + j;
            const float bj = b1[n0 + nl];
            float w2c[C_];
            #pragma unroll
            for (int cc = 0; cc < C_; ++cc) w2c[cc] = w2s[nl][cc];
            #pragma unroll
            for (int ri = 0; ri < 2; ++ri) {
                #pragma unroll
                for (int i = 0; i < 4; ++i) {
                    float h = acc[ri][rj][i][j] + bj;
                    h = h > 0.f ? h : 0.f;
                    #pragma unroll
                    for (int cc = 0; cc < C_; ++cc)
                        ps[ri][i][cc] = fmaf(h, w2c[cc], ps[ri][i][cc]);
                }
            }
        }
    }

    // reduce over tx (low 4 bits of lane)
    #pragma unroll
    for (int off = 1; off < 16; off <<= 1)
        #pragma unroll
        for (int ri = 0; ri < 2; ++ri)
            #pragma unroll
            for (int i = 0; i < 4; ++i)
                #pragma unroll
                for (int cc = 0; cc < C_; ++cc)
                    ps[ri][i][cc] += __shfl_xor(ps[ri][i][cc], off, 64);

    if (tx == 0) {
        #pragma unroll
        for (int ri = 0; ri < 2; ++ri) {
            #pragma unroll
            for (int i = 0; i < 4; ++i) {
                const int m = m0 + ri * 64 + (ty << 2) + i;
                #pragma unroll
                for (int cc = 0; cc < C_; ++cc)
                    atomicAdd(&pot[m * C_ + cc], ps[ri][i][cc]);
            }
        }
    }
}

// -------------------------------------------------------------------------
// Kernel 3: Viterbi decode, one wave (64 threads) per batch. Lanes 0..4 hold
// alpha; cross-lane via __shfl. Strict-> ascending argmax == first-max
// tie-breaking (matches jnp/np.argmax). Also computes seq_length and copies
// chain_kernel to d_out.
// -------------------------------------------------------------------------
__global__ __launch_bounds__(64) void viterbi_kernel(
    const float* __restrict__ pot,       // [B_, S_, C_] (in d_out)
    const float* __restrict__ trans,     // [C_, C_]
    const int* __restrict__ mask,        // [B_, S_]
    float* __restrict__ decoded,         // [B_, S_] (float-encoded ints)
    float* __restrict__ seqlen,          // [B_]
    float* __restrict__ chain_out)       // [C_*C_]
{
    const int b = blockIdx.x;
    const int lane = threadIdx.x;

    __shared__ float pl[S_ * C_];
    __shared__ unsigned char bp[S_][8];
    __shared__ int dec_s[S_];

    const float* pb = pot + b * (S_ * C_);
    for (int i = lane; i < S_ * C_; i += 64) pl[i] = pb[i];

    // seq_length = sum(mask[b])
    int mcnt = 0;
    const int* mb = mask + b * S_;
    for (int i = lane; i < S_; i += 64) mcnt += (mb[i] != 0) ? 1 : 0;
    #pragma unroll
    for (int off = 32; off >= 1; off >>= 1) mcnt += __shfl_xor(mcnt, off, 64);

    if (b == 0 && lane < C_ * C_) chain_out[lane] = trans[lane];

    __syncthreads();

    float tc[C_] = {0.f, 0.f, 0.f, 0.f, 0.f};
    const int c = lane;
    if (c < C_) {
        #pragma unroll
        for (int p = 0; p < C_; ++p) tc[p] = trans[p * C_ + c];
    }
    float alpha = (c < C_) ? pl[c] : -3.0e38f;

    for (int t = 1; t < S_; ++t) {
        float best = -3.0e38f;
        int arg = 0;
        #pragma unroll
        for (int p = 0; p < C_; ++p) {
            const float s = __shfl(alpha, p, 64) + tc[p];
            if (s > best) { best = s; arg = p; }
        }
        if (c < C_) {
            bp[t][c] = (unsigned char)arg;
            alpha = best + pl[t * C_ + c];
        }
    }
    __syncthreads();

    // final argmax over lanes 0..4 (first-max tiebreak)
    float bestA = -3.0e38f;
    int last = 0;
    #pragma unroll
    for (int p = 0; p < C_; ++p) {
        const float ap = __shfl(alpha, p, 64);
        if (ap > bestA) { bestA = ap; last = p; }
    }

    if (lane == 0) {
        int tag = last;
        dec_s[S_ - 1] = tag;
        for (int t = S_ - 1; t >= 1; --t) {
            tag = bp[t][tag];
            dec_s[t - 1] = tag;
        }
        seqlen[b] = (float)mcnt;
    }
    __syncthreads();

    float* db = decoded + b * S_;
    for (int i = lane; i < S_; i += 64) db[i] = (float)dec_s[i];
}

// -------------------------------------------------------------------------
extern "C" void kernel_launch(void* const* d_in, const int* in_sizes, int n_in,
                              void* d_out, int out_size, void* d_ws, size_t ws_size,
                              hipStream_t stream) {
    const float* hs    = (const float*)d_in[0];   // [B,S,D]
    const int*   mask  = (const int*)  d_in[1];   // [B,S]
    const float* W1    = (const float*)d_in[2];   // [D,H]
    const float* b1    = (const float*)d_in[3];   // [H]
    const float* W2    = (const float*)d_in[4];   // [H,C]
    const float* b2    = (const float*)d_in[5];   // [C]
    const float* chain = (const float*)d_in[6];   // [C,C]
    const float* lb    = (const float*)d_in[7];   // [C]
    const float* rb    = (const float*)d_in[8];   // [C]

    float* out      = (float*)d_out;
    float* decoded  = out;                          // 32768
    float* pot      = out + M_;                     // 163840
    float* seq      = out + M_ + M_ * C_;           // 64
    float* chainout = seq + B_;                     // 25

    // 1) pot = b2 + boundaries  (d_out is poisoned before every run)
    init_pot_kernel<<<(M_ * C_ + 255) / 256, 256, 0, stream>>>(b2, lb, rb, pot);

    // 2) fused relu-GEMM + pot accumulation
    dim3 grid(H_ / BN, M_ / BM);   // (6, 256)
    gemm_relu_pot_kernel<<<grid, 256, 0, stream>>>(hs, W1, b1, W2, pot);

    // 3) viterbi + seq_length + chain_kernel passthrough
    viterbi_kernel<<<B_, 64, 0, stream>>>(pot, chain, mask, decoded, seq, chainout);
}

// Round 2
// 605.633 us; speedup vs baseline: 1.0890x; 1.0890x over previous
//
#include <hip/hip_runtime.h>

// Problem constants
#define B_  64
#define S_  512
#define D_  768
#define H_  768
#define C_  5
#define M_  (B_ * S_)        // 32768 rows

typedef _Float16 half8 __attribute__((ext_vector_type(8)));
typedef float f32x4 __attribute__((ext_vector_type(4)));

#define W1T_ELEMS (D_ * H_)  // 589824

// =========================================================================
// Kernel 1: init pot = b2 + boundaries (pot lives in d_out; re-poisoned each run)
// =========================================================================
__global__ __launch_bounds__(256) void init_pot_kernel(
    const float* __restrict__ b2, const float* __restrict__ lb,
    const float* __restrict__ rb, float* __restrict__ pot)
{
    const int idx = blockIdx.x * 256 + threadIdx.x;
    if (idx < M_ * C_) {
        const int c = idx % C_;
        const int t = (idx / C_) & (S_ - 1);
        float v = b2[c];
        if (t == 0)      v += lb[c];
        if (t == S_ - 1) v += rb[c];
        pot[idx] = v;
    }
}

// =========================================================================
// Kernel 2a: prep — W1 [k][n] fp32  ->  W1t_hi/lo [n][k] f16 split (in d_ws)
// =========================================================================
__global__ __launch_bounds__(256) void prep_w1_kernel(
    const float* __restrict__ W1,
    _Float16* __restrict__ w1h, _Float16* __restrict__ w1l)
{
    const int n = blockIdx.x;                 // 768 output rows
    for (int k = threadIdx.x; k < D_; k += 256) {
        const float w = W1[k * H_ + n];
        const _Float16 h = (_Float16)w;
        w1h[n * D_ + k] = h;
        w1l[n * D_ + k] = (_Float16)(w - (float)h);
    }
}

// =========================================================================
// Kernel 2b: MFMA split-f16 GEMM  h = relu(X@W1 + b1), pot += h@W2 (atomics)
// 128x128x32 tile, 4 waves, each wave 64x64 via 4x4 MFMAs of 16x16x32_f16.
// 3 MFMA products per fragment pair: Ah*Bh + Al*Bh + Ah*Bl  (~22-bit mantissa).
// =========================================================================
#define LDA 40   // padded f16 row stride (80 B): uniform bank spread for b128

__global__ void gemm_mfma_kernel(
    const float* __restrict__ X,          // [M_, D_] fp32
    const _Float16* __restrict__ w1h,     // [H_, D_] f16 (n-major!)
    const _Float16* __restrict__ w1l,
    const float* __restrict__ b1,
    const float* __restrict__ W2,         // [H_, C_]
    float* __restrict__ pot)              // [M_, C_] pre-initialized
{
    __shared__ _Float16 Ah[128 * LDA];
    __shared__ _Float16 Al[128 * LDA];
    __shared__ _Float16 Bh[128 * LDA];
    __shared__ _Float16 Bl[128 * LDA];

    const int tid  = threadIdx.x;
    const int m0   = blockIdx.y * 128;
    const int n0   = blockIdx.x * 128;
    const int lane = tid & 63;
    const int w    = tid >> 6;
    const int wm   = w >> 1, wn = w & 1;
    const int i15  = lane & 15, quad = lane >> 4;

    // staging: 2 threads per row, 16 elements each
    const int arow = tid >> 1, ac = (tid & 1) * 16;
    const float*    aptr  = X   + (size_t)(m0 + arow) * D_ + ac;
    const _Float16* bhptr = w1h + (size_t)(n0 + arow) * D_ + ac;
    const _Float16* blptr = w1l + (size_t)(n0 + arow) * D_ + ac;

    f32x4 acc[4][4];
    #pragma unroll
    for (int mi = 0; mi < 4; ++mi)
        #pragma unroll
        for (int ni = 0; ni < 4; ++ni)
            acc[mi][ni] = (f32x4){0.f, 0.f, 0.f, 0.f};

    float4 av[4];
    uint4  bh2[2], bl2[2];

    // prologue: load k-tile 0
    {
        #pragma unroll
        for (int i = 0; i < 4; ++i) av[i] = *(const float4*)(aptr + 4 * i);
        bh2[0] = *(const uint4*)(bhptr);     bh2[1] = *(const uint4*)(bhptr + 8);
        bl2[0] = *(const uint4*)(blptr);     bl2[1] = *(const uint4*)(blptr + 8);
    }

    for (int kt = 0; kt < D_ / 32; ++kt) {
        __syncthreads();   // previous iter's fragment reads done

        // ---- write staged regs to LDS (A converted to hi/lo f16) ----
        {
            float axf[16];
            #pragma unroll
            for (int i = 0; i < 4; ++i) *(float4*)&axf[4 * i] = av[i];
            half8 hh[2], hl[2];
            #pragma unroll
            for (int i = 0; i < 16; ++i) {
                const _Float16 h = (_Float16)axf[i];
                hh[i >> 3][i & 7] = h;
                hl[i >> 3][i & 7] = (_Float16)(axf[i] - (float)h);
            }
            *(half8*)&Ah[arow * LDA + ac]     = hh[0];
            *(half8*)&Ah[arow * LDA + ac + 8] = hh[1];
            *(half8*)&Al[arow * LDA + ac]     = hl[0];
            *(half8*)&Al[arow * LDA + ac + 8] = hl[1];
            *(uint4*)&Bh[arow * LDA + ac]     = bh2[0];
            *(uint4*)&Bh[arow * LDA + ac + 8] = bh2[1];
            *(uint4*)&Bl[arow * LDA + ac]     = bl2[0];
            *(uint4*)&Bl[arow * LDA + ac + 8] = bl2[1];
        }
        __syncthreads();

        // ---- prefetch next k-tile while MFMAs run ----
        if (kt + 1 < D_ / 32) {
            const int o = (kt + 1) * 32;
            #pragma unroll
            for (int i = 0; i < 4; ++i) av[i] = *(const float4*)(aptr + o + 4 * i);
            bh2[0] = *(const uint4*)(bhptr + o);  bh2[1] = *(const uint4*)(bhptr + o + 8);
            bl2[0] = *(const uint4*)(blptr + o);  bl2[1] = *(const uint4*)(blptr + o + 8);
        }

        // ---- fragments + MFMA ----
        half8 afh[4], afl[4];
        #pragma unroll
        for (int mi = 0; mi < 4; ++mi) {
            const int r = (wm * 64 + mi * 16 + i15) * LDA + quad * 8;
            afh[mi] = *(const half8*)&Ah[r];
            afl[mi] = *(const half8*)&Al[r];
        }
        #pragma unroll
        for (int ni = 0; ni < 4; ++ni) {
            const int r = (wn * 64 + ni * 16 + i15) * LDA + quad * 8;
            const half8 bfh = *(const half8*)&Bh[r];
            const half8 bfl = *(const half8*)&Bl[r];
            #pragma unroll
            for (int mi = 0; mi < 4; ++mi) {
                acc[mi][ni] = __builtin_amdgcn_mfma_f32_16x16x32_f16(afh[mi], bfh, acc[mi][ni], 0, 0, 0);
                acc[mi][ni] = __builtin_amdgcn_mfma_f32_16x16x32_f16(afl[mi], bfh, acc[mi][ni], 0, 0, 0);
                acc[mi][ni] = __builtin_amdgcn_mfma_f32_16x16x32_f16(afh[mi], bfl, acc[mi][ni], 0, 0, 0);
            }
        }
    }

    // ---- epilogue: relu(h + b1) @ W2 -> atomic pot ----
    // C/D layout: col = lane&15, row = quad*4 + reg  [m89-verified]
    float b1v[4], w2v[4][C_];
    #pragma unroll
    for (int ni = 0; ni < 4; ++ni) {
        const int col = n0 + wn * 64 + ni * 16 + i15;
        b1v[ni] = b1[col];
        #pragma unroll
        for (int cc = 0; cc < C_; ++cc) w2v[ni][cc] = W2[col * C_ + cc];
    }

    #pragma unroll
    for (int mi = 0; mi < 4; ++mi) {
        float ps[4][C_];
        #pragma unroll
        for (int r = 0; r < 4; ++r)
            #pragma unroll
            for (int cc = 0; cc < C_; ++cc) ps[r][cc] = 0.f;

        #pragma unroll
        for (int ni = 0; ni < 4; ++ni)
            #pragma unroll
            for (int r = 0; r < 4; ++r) {
                float h = acc[mi][ni][r] + b1v[ni];
                h = h > 0.f ? h : 0.f;
                #pragma unroll
                for (int cc = 0; cc < C_; ++cc)
                    ps[r][cc] = fmaf(h, w2v[ni][cc], ps[r][cc]);
            }

        #pragma unroll
        for (int off = 1; off < 16; off <<= 1)
            #pragma unroll
            for (int r = 0; r < 4; ++r)
                #pragma unroll
                for (int cc = 0; cc < C_; ++cc)
                    ps[r][cc] += __shfl_xor(ps[r][cc], off, 64);

        if (i15 == 0) {
            #pragma unroll
            for (int r = 0; r < 4; ++r) {
                const int m = m0 + wm * 64 + mi * 16 + quad * 4 + r;
                #pragma unroll
                for (int cc = 0; cc < C_; ++cc)
                    atomicAdd(&pot[m * C_ + cc], ps[r][cc]);
            }
        }
    }
}

// =========================================================================
// Fallback fp32 GEMM (round-1 kernel) in case ws_size is too small
// =========================================================================
#define FBM 128
#define FBN 128
#define FBK 8
#define FLDS 132

__global__ __launch_bounds__(256) void gemm_relu_pot_kernel(
    const float* __restrict__ X, const float* __restrict__ W1,
    const float* __restrict__ b1, const float* __restrict__ W2,
    float* __restrict__ pot)
{
    __shared__ float As[FBK * FLDS];
    __shared__ float Bs[FBK * FLDS];
    __shared__ float w2s[FBN][C_];

    const int tid = threadIdx.x;
    const int tx  = tid & 15;
    const int ty  = tid >> 4;
    const int m0  = blockIdx.y * FBM;
    const int n0  = blockIdx.x * FBN;

    for (int idx = tid; idx < FBN * C_; idx += 256)
        w2s[idx / C_][idx % C_] = W2[(n0 + idx / C_) * C_ + idx % C_];

    float acc[2][2][4][4];
    #pragma unroll
    for (int a = 0; a < 2; ++a)
        #pragma unroll
        for (int b = 0; b < 2; ++b)
            #pragma unroll
            for (int i = 0; i < 4; ++i)
                #pragma unroll
                for (int j = 0; j < 4; ++j) acc[a][b][i][j] = 0.f;

    const int arow = tid >> 1, aq = tid & 1;
    const int brow = tid >> 5, bq = tid & 31;
    const float* Aptr = X  + (m0 + arow) * D_ + aq * 4;
    const float* Bptr = W1 + brow * H_ + n0 + bq * 4;

    for (int kt = 0; kt < D_; kt += FBK) {
        const float4 avv = *(const float4*)Aptr;
        const float4 bvv = *(const float4*)Bptr;
        __syncthreads();
        As[(aq * 4 + 0) * FLDS + arow] = avv.x;
        As[(aq * 4 + 1) * FLDS + arow] = avv.y;
        As[(aq * 4 + 2) * FLDS + arow] = avv.z;
        As[(aq * 4 + 3) * FLDS + arow] = avv.w;
        *(float4*)&Bs[brow * FLDS + bq * 4] = bvv;
        __syncthreads();

        #pragma unroll
        for (int k = 0; k < FBK; ++k) {
            const float4 a0 = *(const float4*)&As[k * FLDS + (ty << 2)];
            const float4 a1 = *(const float4*)&As[k * FLDS + 64 + (ty << 2)];
            const float4 bb0 = *(const float4*)&Bs[k * FLDS + (tx << 2)];
            const float4 bb1 = *(const float4*)&Bs[k * FLDS + 64 + (tx << 2)];
            const float ar[2][4] = {{a0.x, a0.y, a0.z, a0.w}, {a1.x, a1.y, a1.z, a1.w}};
            const float br[2][4] = {{bb0.x, bb0.y, bb0.z, bb0.w}, {bb1.x, bb1.y, bb1.z, bb1.w}};
            #pragma unroll
            for (int ri = 0; ri < 2; ++ri)
                #pragma unroll
                for (int i = 0; i < 4; ++i)
                    #pragma unroll
                    for (int rj = 0; rj < 2; ++rj)
                        #pragma unroll
                        for (int j = 0; j < 4; ++j)
                            acc[ri][rj][i][j] = fmaf(ar[ri][i], br[rj][j], acc[ri][rj][i][j]);
        }
        Aptr += FBK;
        Bptr += FBK * H_;
    }

    float ps[2][4][C_];
    #pragma unroll
    for (int ri = 0; ri < 2; ++ri)
        #pragma unroll
        for (int i = 0; i < 4; ++i)
            #pragma unroll
            for (int cc = 0; cc < C_; ++cc) ps[ri][i][cc] = 0.f;

    #pragma unroll
    for (int rj = 0; rj < 2; ++rj)
        #pragma unroll
        for (int j = 0; j < 4; ++j) {
            const int nl = rj * 64 + (tx << 2) + j;
            const float bj = b1[n0 + nl];
            float w2c[C_];
            #pragma unroll
            for (int cc = 0; cc < C_; ++cc) w2c[cc] = w2s[nl][cc];
            #pragma unroll
            for (int ri = 0; ri < 2; ++ri)
                #pragma unroll
                for (int i = 0; i < 4; ++i) {
                    float h = acc[ri][rj][i][j] + bj;
                    h = h > 0.f ? h : 0.f;
                    #pragma unroll
                    for (int cc = 0; cc < C_; ++cc)
                        ps[ri][i][cc] = fmaf(h, w2c[cc], ps[ri][i][cc]);
                }
        }

    #pragma unroll
    for (int off = 1; off < 16; off <<= 1)
        #pragma unroll
        for (int ri = 0; ri < 2; ++ri)
            #pragma unroll
            for (int i = 0; i < 4; ++i)
                #pragma unroll
                for (int cc = 0; cc < C_; ++cc)
                    ps[ri][i][cc] += __shfl_xor(ps[ri][i][cc], off, 64);

    if (tx == 0)
        #pragma unroll
        for (int ri = 0; ri < 2; ++ri)
            #pragma unroll
            for (int i = 0; i < 4; ++i) {
                const int m = m0 + ri * 64 + (ty << 2) + i;
                #pragma unroll
                for (int cc = 0; cc < C_; ++cc)
                    atomicAdd(&pot[m * C_ + cc], ps[ri][i][cc]);
            }
}

// =========================================================================
// Kernel 3: Viterbi decode (unchanged from R1, verified correct)
// =========================================================================
__global__ __launch_bounds__(64) void viterbi_kernel(
    const float* __restrict__ pot, const float* __restrict__ trans,
    const int* __restrict__ mask, float* __restrict__ decoded,
    float* __restrict__ seqlen, float* __restrict__ chain_out)
{
    const int b = blockIdx.x;
    const int lane = threadIdx.x;

    __shared__ float pl[S_ * C_];
    __shared__ unsigned char bp[S_][8];
    __shared__ int dec_s[S_];

    const float* pb = pot + b * (S_ * C_);
    for (int i = lane; i < S_ * C_; i += 64) pl[i] = pb[i];

    int mcnt = 0;
    const int* mb = mask + b * S_;
    for (int i = lane; i < S_; i += 64) mcnt += (mb[i] != 0) ? 1 : 0;
    #pragma unroll
    for (int off = 32; off >= 1; off >>= 1) mcnt += __shfl_xor(mcnt, off, 64);

    if (b == 0 && lane < C_ * C_) chain_out[lane] = trans[lane];

    __syncthreads();

    float tc[C_] = {0.f, 0.f, 0.f, 0.f, 0.f};
    const int c = lane;
    if (c < C_) {
        #pragma unroll
        for (int p = 0; p < C_; ++p) tc[p] = trans[p * C_ + c];
    }
    float alpha = (c < C_) ? pl[c] : -3.0e38f;

    for (int t = 1; t < S_; ++t) {
        float best = -3.0e38f;
        int arg = 0;
        #pragma unroll
        for (int p = 0; p < C_; ++p) {
            const float s = __shfl(alpha, p, 64) + tc[p];
            if (s > best) { best = s; arg = p; }
        }
        if (c < C_) {
            bp[t][c] = (unsigned char)arg;
            alpha = best + pl[t * C_ + c];
        }
    }
    __syncthreads();

    float bestA = -3.0e38f;
    int last = 0;
    #pragma unroll
    for (int p = 0; p < C_; ++p) {
        const float ap = __shfl(alpha, p, 64);
        if (ap > bestA) { bestA = ap; last = p; }
    }

    if (lane == 0) {
        int tag = last;
        dec_s[S_ - 1] = tag;
        for (int t = S_ - 1; t >= 1; --t) {
            tag = bp[t][tag];
            dec_s[t - 1] = tag;
        }
        seqlen[b] = (float)mcnt;
    }
    __syncthreads();

    float* db = decoded + b * S_;
    for (int i = lane; i < S_; i += 64) db[i] = (float)dec_s[i];
}

// =========================================================================
extern "C" void kernel_launch(void* const* d_in, const int* in_sizes, int n_in,
                              void* d_out, int out_size, void* d_ws, size_t ws_size,
                              hipStream_t stream) {
    const float* hs    = (const float*)d_in[0];
    const int*   mask  = (const int*)  d_in[1];
    const float* W1    = (const float*)d_in[2];
    const float* b1    = (const float*)d_in[3];
    const float* W2    = (const float*)d_in[4];
    const float* b2    = (const float*)d_in[5];
    const float* chain = (const float*)d_in[6];
    const float* lb    = (const float*)d_in[7];
    const float* rb    = (const float*)d_in[8];

    float* out      = (float*)d_out;
    float* decoded  = out;
    float* pot      = out + M_;
    float* seq      = out + M_ + M_ * C_;
    float* chainout = seq + B_;

    init_pot_kernel<<<(M_ * C_ + 255) / 256, 256, 0, stream>>>(b2, lb, rb, pot);

    const size_t need = (size_t)W1T_ELEMS * 2 * sizeof(_Float16);  // 2.36 MB
    if (ws_size >= need) {
        _Float16* w1h = (_Float16*)d_ws;
        _Float16* w1l = w1h + W1T_ELEMS;
        prep_w1_kernel<<<H_, 256, 0, stream>>>(W1, w1h, w1l);
        dim3 grid(H_ / 128, M_ / 128);   // (6, 256)
        gemm_mfma_kernel<<<grid, 256, 0, stream>>>(hs, w1h, w1l, b1, W2, pot);
    } else {
        dim3 grid(H_ / FBN, M_ / FBM);
        gemm_relu_pot_kernel<<<grid, 256, 0, stream>>>(hs, W1, b1, W2, pot);
    }

    viterbi_kernel<<<B_, 64, 0, stream>>>(pot, chain, mask, decoded, seq, chainout);
}

// Round 3
// 346.757 us; speedup vs baseline: 1.9020x; 1.7466x over previous
//
#include <hip/hip_runtime.h>

// Problem constants
#define B_  64
#define S_  512
#define D_  768
#define H_  768
#define C_  5
#define M_  (B_ * S_)        // 32768 rows

typedef float f32x4 __attribute__((ext_vector_type(4)));
typedef short short8 __attribute__((ext_vector_type(8)));   // bf16x8 MFMA operand

#define W1T_ELEMS (D_ * H_)  // 589824 (bf16 in ws: 1.18 MB)

__device__ __forceinline__ unsigned short f2bf(float f) {
    unsigned int u = __float_as_uint(f);
    u += 0x7FFFu + ((u >> 16) & 1u);     // RNE
    return (unsigned short)(u >> 16);
}

// =========================================================================
// Kernel 1: init pot = b2 + boundaries (pot lives in d_out; poisoned each run)
// =========================================================================
__global__ __launch_bounds__(256) void init_pot_kernel(
    const float* __restrict__ b2, const float* __restrict__ lb,
    const float* __restrict__ rb, float* __restrict__ pot)
{
    const int idx = blockIdx.x * 256 + threadIdx.x;
    if (idx < M_ * C_) {
        const int c = idx % C_;
        const int t = (idx / C_) & (S_ - 1);
        float v = b2[c];
        if (t == 0)      v += lb[c];
        if (t == S_ - 1) v += rb[c];
        pot[idx] = v;
    }
}

// =========================================================================
// Kernel 2a: W1 [k][n] fp32 -> w1t [n][k] bf16 (LDS-tiled transpose)
// =========================================================================
__global__ __launch_bounds__(256) void prep_w1_kernel(
    const float* __restrict__ W1, unsigned short* __restrict__ w1t)
{
    __shared__ float t[32][33];
    const int bx = blockIdx.x;            // n tile (24)
    const int by = blockIdx.y;            // k tile (24)
    const int lx = threadIdx.x & 31, ly = threadIdx.x >> 5;   // 32 x 8
    #pragma unroll
    for (int j = 0; j < 4; ++j)
        t[ly + 8 * j][lx] = W1[(by * 32 + ly + 8 * j) * H_ + bx * 32 + lx];
    __syncthreads();
    #pragma unroll
    for (int j = 0; j < 4; ++j)
        w1t[(size_t)(bx * 32 + ly + 8 * j) * D_ + by * 32 + lx] = f2bf(t[lx][ly + 8 * j]);
}

// =========================================================================
// Kernel 2b: bf16 MFMA GEMM  h = relu(X@W1 + b1), pot += h@W2
// 128x128 tile, BK=32, global_load_lds staging, chunk-major LDS layout
// (slot = row%16 + 16*chunk per 16-row group -> conflict-free b128 frag reads).
// A staged as fp32 (cvt->bf16 at fragment read); B staged bf16 from ws.
// Epilogue: per-wave h@W2 partial -> LDS -> 640 atomics/block.
// =========================================================================
__device__ __forceinline__ void gload16(const void* g, void* l) {
    __builtin_amdgcn_global_load_lds(
        (const __attribute__((address_space(1))) unsigned int*)g,
        (__attribute__((address_space(3))) unsigned int*)l, 16, 0, 0);
}

__global__ __launch_bounds__(256) void gemm_bf16_kernel(
    const float* __restrict__ X,              // [M_, D_] fp32
    const unsigned short* __restrict__ w1t,   // [H_, D_] bf16 (n-major)
    const float* __restrict__ b1,
    const float* __restrict__ W2,             // [H_, C_]
    float* __restrict__ pot)                  // [M_, C_] pre-initialized
{
    __shared__ __align__(16) float          Asm[128 * 32];          // 16 KB
    __shared__ __align__(16) unsigned short Bsm[128 * 32];          // 8 KB
    __shared__ float pp[2][128][C_];                                // 5 KB

    const int tid  = threadIdx.x;
    const int lane = tid & 63, w = tid >> 6;
    const int wm   = w >> 1, wn = w & 1;
    const int i15  = lane & 15, quad = lane >> 4;

    // XCD swizzle: 6 n-blocks of an m-tile land on the same XCD (bid%8)
    const int bid = blockIdx.x;
    const int r8 = bid & 7, q8 = bid >> 3;
    const int nb = q8 % 6, mhi = q8 / 6;
    const int m0 = (mhi * 8 + r8) * 128;
    const int n0 = nb * 128;

    // ---- staging pointers: wave w owns A-instrs 4w..4w+3, B-instrs 2w..2w+1
    const float* gA[4];
    float* lA[4];
    const unsigned short* gB[2];
    unsigned short* lB[2];
    #pragma unroll
    for (int i = 0; i < 4; ++i) {
        const int a = 4 * w + i, g = a >> 1, h = a & 1;
        gA[i] = X + (size_t)(m0 + g * 16 + i15) * D_ + (4 * h + quad) * 4;
        lA[i] = &Asm[g * 512 + h * 256];          // uniform base; lane*16B auto
    }
    #pragma unroll
    for (int i = 0; i < 2; ++i) {
        const int b = 2 * w + i;
        gB[i] = w1t + (size_t)(n0 + b * 16 + i15) * D_ + quad * 8;
        lB[i] = &Bsm[b * 512];
    }

    f32x4 acc[4][4];
    #pragma unroll
    for (int mi = 0; mi < 4; ++mi)
        #pragma unroll
        for (int ni = 0; ni < 4; ++ni)
            acc[mi][ni] = (f32x4){0.f, 0.f, 0.f, 0.f};

    for (int kt = 0; kt < D_ / 32; ++kt) {
        __syncthreads();                      // prev iter's fragment reads done
        #pragma unroll
        for (int i = 0; i < 4; ++i) { gload16(gA[i], lA[i]); gA[i] += 32; }
        #pragma unroll
        for (int i = 0; i < 2; ++i) { gload16(gB[i], lB[i]); gB[i] += 32; }
        __syncthreads();                      // vmcnt(0) drain inserted here

        short8 af[4];
        #pragma unroll
        for (int mi = 0; mi < 4; ++mi) {
            const int row = wm * 64 + mi * 16 + i15;
            const int base = (row >> 4) * 512 + (row & 15) * 4 + quad * 128;
            const f32x4 lo = *(const f32x4*)&Asm[base];
            const f32x4 hi = *(const f32x4*)&Asm[base + 64];
            float f[8];
            *(f32x4*)&f[0] = lo; *(f32x4*)&f[4] = hi;
            union { short8 s; unsigned short u[8]; } cv;
            #pragma unroll
            for (int j = 0; j < 8; ++j) cv.u[j] = f2bf(f[j]);
            af[mi] = cv.s;
        }
        short8 bfr[4];
        #pragma unroll
        for (int ni = 0; ni < 4; ++ni) {
            const int row = wn * 64 + ni * 16 + i15;
            const int base = (row >> 4) * 512 + quad * 128 + (row & 15) * 8;
            bfr[ni] = *(const short8*)&Bsm[base];
        }
        #pragma unroll
        for (int ni = 0; ni < 4; ++ni)
            #pragma unroll
            for (int mi = 0; mi < 4; ++mi)
                acc[mi][ni] = __builtin_amdgcn_mfma_f32_16x16x32_bf16(
                    af[mi], bfr[ni], acc[mi][ni], 0, 0, 0);
    }

    // ---- epilogue: relu(h+b1)@W2, wave-partial -> LDS -> block atomics ----
    float b1v[4], w2v[4][C_];
    #pragma unroll
    for (int ni = 0; ni < 4; ++ni) {
        const int col = n0 + wn * 64 + ni * 16 + i15;
        b1v[ni] = b1[col];
        #pragma unroll
        for (int cc = 0; cc < C_; ++cc) w2v[ni][cc] = W2[col * C_ + cc];
    }

    #pragma unroll
    for (int mi = 0; mi < 4; ++mi) {
        float ps[4][C_];
        #pragma unroll
        for (int r = 0; r < 4; ++r)
            #pragma unroll
            for (int cc = 0; cc < C_; ++cc) ps[r][cc] = 0.f;

        #pragma unroll
        for (int ni = 0; ni < 4; ++ni)
            #pragma unroll
            for (int r = 0; r < 4; ++r) {
                float h = acc[mi][ni][r] + b1v[ni];
                h = h > 0.f ? h : 0.f;
                #pragma unroll
                for (int cc = 0; cc < C_; ++cc)
                    ps[r][cc] = fmaf(h, w2v[ni][cc], ps[r][cc]);
            }

        #pragma unroll
        for (int off = 1; off < 16; off <<= 1)
            #pragma unroll
            for (int r = 0; r < 4; ++r)
                #pragma unroll
                for (int cc = 0; cc < C_; ++cc)
                    ps[r][cc] += __shfl_xor(ps[r][cc], off, 64);

        if (i15 == 0) {
            #pragma unroll
            for (int r = 0; r < 4; ++r) {
                const int row = wm * 64 + mi * 16 + quad * 4 + r;
                #pragma unroll
                for (int cc = 0; cc < C_; ++cc)
                    pp[wn][row][cc] = ps[r][cc];
            }
        }
    }
    __syncthreads();

    for (int idx = tid; idx < 128 * C_; idx += 256) {
        const int row = idx / C_, cc = idx % C_;
        atomicAdd(&pot[(size_t)(m0 + row) * C_ + cc],
                  pp[0][row][cc] + pp[1][row][cc]);
    }
}

// =========================================================================
// Fallback fp32 GEMM (round-1 kernel, proven) if ws too small
// =========================================================================
#define FBK 8
#define FLDS 132
__global__ __launch_bounds__(256) void gemm_relu_pot_kernel(
    const float* __restrict__ X, const float* __restrict__ W1,
    const float* __restrict__ b1, const float* __restrict__ W2,
    float* __restrict__ pot)
{
    __shared__ float As[FBK * FLDS];
    __shared__ float Bs[FBK * FLDS];
    __shared__ float w2s[128][C_];

    const int tid = threadIdx.x;
    const int tx = tid & 15, ty = tid >> 4;
    const int m0 = blockIdx.y * 128, n0 = blockIdx.x * 128;

    for (int idx = tid; idx < 128 * C_; idx += 256)
        w2s[idx / C_][idx % C_] = W2[(n0 + idx / C_) * C_ + idx % C_];

    float acc[2][2][4][4];
    #pragma unroll
    for (int a = 0; a < 2; ++a)
        #pragma unroll
        for (int b = 0; b < 2; ++b)
            #pragma unroll
            for (int i = 0; i < 4; ++i)
                #pragma unroll
                for (int j = 0; j < 4; ++j) acc[a][b][i][j] = 0.f;

    const int arow = tid >> 1, aq = tid & 1;
    const int brow = tid >> 5, bq = tid & 31;
    const float* Aptr = X + (m0 + arow) * D_ + aq * 4;
    const float* Bptr = W1 + brow * H_ + n0 + bq * 4;

    for (int kt = 0; kt < D_; kt += FBK) {
        const float4 avv = *(const float4*)Aptr;
        const float4 bvv = *(const float4*)Bptr;
        __syncthreads();
        As[(aq * 4 + 0) * FLDS + arow] = avv.x;
        As[(aq * 4 + 1) * FLDS + arow] = avv.y;
        As[(aq * 4 + 2) * FLDS + arow] = avv.z;
        As[(aq * 4 + 3) * FLDS + arow] = avv.w;
        *(float4*)&Bs[brow * FLDS + bq * 4] = bvv;
        __syncthreads();
        #pragma unroll
        for (int k = 0; k < FBK; ++k) {
            const float4 a0 = *(const float4*)&As[k * FLDS + (ty << 2)];
            const float4 a1 = *(const float4*)&As[k * FLDS + 64 + (ty << 2)];
            const float4 b0 = *(const float4*)&Bs[k * FLDS + (tx << 2)];
            const float4 b1r = *(const float4*)&Bs[k * FLDS + 64 + (tx << 2)];
            const float ar[2][4] = {{a0.x,a0.y,a0.z,a0.w},{a1.x,a1.y,a1.z,a1.w}};
            const float br[2][4] = {{b0.x,b0.y,b0.z,b0.w},{b1r.x,b1r.y,b1r.z,b1r.w}};
            #pragma unroll
            for (int ri = 0; ri < 2; ++ri)
                #pragma unroll
                for (int i = 0; i < 4; ++i)
                    #pragma unroll
                    for (int rj = 0; rj < 2; ++rj)
                        #pragma unroll
                        for (int j = 0; j < 4; ++j)
                            acc[ri][rj][i][j] = fmaf(ar[ri][i], br[rj][j], acc[ri][rj][i][j]);
        }
        Aptr += FBK;
        Bptr += FBK * H_;
    }

    float ps[2][4][C_];
    #pragma unroll
    for (int ri = 0; ri < 2; ++ri)
        #pragma unroll
        for (int i = 0; i < 4; ++i)
            #pragma unroll
            for (int cc = 0; cc < C_; ++cc) ps[ri][i][cc] = 0.f;

    #pragma unroll
    for (int rj = 0; rj < 2; ++rj)
        #pragma unroll
        for (int j = 0; j < 4; ++j) {
            const int nl = rj * 64 + (tx << 2) + j;
            const float bj = b1[n0 + nl];
            float w2c[C_];
            #pragma unroll
            for (int cc = 0; cc < C_; ++cc) w2c[cc] = w2s[nl][cc];
            #pragma unroll
            for (int ri = 0; ri < 2; ++ri)
                #pragma unroll
                for (int i = 0; i < 4; ++i) {
                    float h = acc[ri][rj][i][j] + bj;
                    h = h > 0.f ? h : 0.f;
                    #pragma unroll
                    for (int cc = 0; cc < C_; ++cc)
                        ps[ri][i][cc] = fmaf(h, w2c[cc], ps[ri][i][cc]);
                }
        }

    #pragma unroll
    for (int off = 1; off < 16; off <<= 1)
        #pragma unroll
        for (int ri = 0; ri < 2; ++ri)
            #pragma unroll
            for (int i = 0; i < 4; ++i)
                #pragma unroll
                for (int cc = 0; cc < C_; ++cc)
                    ps[ri][i][cc] += __shfl_xor(ps[ri][i][cc], off, 64);

    if (tx == 0)
        #pragma unroll
        for (int ri = 0; ri < 2; ++ri)
            #pragma unroll
            for (int i = 0; i < 4; ++i) {
                const int m = m0 + ri * 64 + (ty << 2) + i;
                #pragma unroll
                for (int cc = 0; cc < C_; ++cc)
                    atomicAdd(&pot[m * C_ + cc], ps[ri][i][cc]);
            }
}

// =========================================================================
// Kernel 3: Viterbi. Fwd loop: lanes 0..4 via shfl (proven). Backtrace:
// packed 3-bit maps, 64x8-segment composition + lane-0 prefix (O(8) depth).
// =========================================================================
__global__ __launch_bounds__(64) void viterbi_kernel(
    const float* __restrict__ pot, const float* __restrict__ trans,
    const int* __restrict__ mask, float* __restrict__ decoded,
    float* __restrict__ seqlen, float* __restrict__ chain_out)
{
    const int b = blockIdx.x;
    const int lane = threadIdx.x;

    __shared__ float pl[S_ * C_];
    __shared__ unsigned char bpb[S_][8];
    __shared__ unsigned int bpk[S_];
    __shared__ unsigned int gseg[64];
    __shared__ int bt[64];
    __shared__ int dec_s[S_];

    const float* pb = pot + b * (S_ * C_);
    for (int i = lane; i < S_ * C_; i += 64) pl[i] = pb[i];

    int mcnt = 0;
    const int* mb = mask + b * S_;
    for (int i = lane; i < S_; i += 64) mcnt += (mb[i] != 0) ? 1 : 0;
    #pragma unroll
    for (int off = 32; off >= 1; off >>= 1) mcnt += __shfl_xor(mcnt, off, 64);

    if (b == 0 && lane < C_ * C_) chain_out[lane] = trans[lane];

    __syncthreads();

    float tc[C_] = {0.f, 0.f, 0.f, 0.f, 0.f};
    const int c = lane;
    if (c < C_) {
        #pragma unroll
        for (int p = 0; p < C_; ++p) tc[p] = trans[p * C_ + c];
    }
    float alpha = (c < C_) ? pl[c] : -3.0e38f;

    for (int t = 1; t < S_; ++t) {
        float best = -3.0e38f;
        int arg = 0;
        #pragma unroll
        for (int p = 0; p < C_; ++p) {
            const float s = __shfl(alpha, p, 64) + tc[p];
            if (s > best) { best = s; arg = p; }
        }
        if (c < C_) {
            bpb[t][c] = (unsigned char)arg;
            alpha = best + pl[t * C_ + c];
        }
    }

    // final argmax (first-max) -> uniform across lanes
    float bestA = -3.0e38f;
    int last = 0;
    #pragma unroll
    for (int p = 0; p < C_; ++p) {
        const float ap = __shfl(alpha, p, 64);
        if (ap > bestA) { bestA = ap; last = p; }
    }
    __syncthreads();

    // pack maps: bpk[t] = 5 x 3-bit entries
    for (int t = lane; t < S_; t += 64) {
        unsigned int m = 0;
        #pragma unroll
        for (int x = 0; x < C_; ++x) m |= (unsigned int)bpb[t][x] << (3 * x);
        bpk[t] = m;
    }
    __syncthreads();

    // segment composition: lane l covers t in [8l, 8l+7]
    unsigned int g = 0u | (1u << 3) | (2u << 6) | (3u << 9) | (4u << 12);
    #pragma unroll
    for (int j = 7; j >= 0; --j) {
        const int t = 8 * lane + j;
        if (t >= 1) {
            const unsigned int m = bpk[t];
            unsigned int ng = 0;
            #pragma unroll
            for (int x = 0; x < C_; ++x) {
                const unsigned int gx = (g >> (3 * x)) & 7u;
                ng |= ((m >> (3 * gx)) & 7u) << (3 * x);
            }
            g = ng;
        }
    }
    gseg[lane] = g;
    __syncthreads();

    if (lane == 0) {
        int cur = last;
        for (int l = 63; l >= 0; --l) {
            bt[l] = cur;                       // tag_{8l+7}
            cur = (int)((gseg[l] >> (3 * cur)) & 7u);
        }
        seqlen[b] = (float)mcnt;
    }
    __syncthreads();

    // replay 8 steps per lane
    {
        int tag = bt[lane];
        const int t0 = 8 * lane;
        dec_s[t0 + 7] = tag;
        #pragma unroll
        for (int t = t0 + 7; t >= t0 + 1; --t) {
            tag = (int)((bpk[t] >> (3 * tag)) & 7u);
            dec_s[t - 1] = tag;
        }
    }
    __syncthreads();

    float* db = decoded + b * S_;
    for (int i = lane; i < S_; i += 64) db[i] = (float)dec_s[i];
}

// =========================================================================
extern "C" void kernel_launch(void* const* d_in, const int* in_sizes, int n_in,
                              void* d_out, int out_size, void* d_ws, size_t ws_size,
                              hipStream_t stream) {
    const float* hs    = (const float*)d_in[0];
    const int*   mask  = (const int*)  d_in[1];
    const float* W1    = (const float*)d_in[2];
    const float* b1    = (const float*)d_in[3];
    const float* W2    = (const float*)d_in[4];
    const float* b2    = (const float*)d_in[5];
    const float* chain = (const float*)d_in[6];
    const float* lb    = (const float*)d_in[7];
    const float* rb    = (const float*)d_in[8];

    float* out      = (float*)d_out;
    float* decoded  = out;
    float* pot      = out + M_;
    float* seq      = out + M_ + M_ * C_;
    float* chainout = seq + B_;

    init_pot_kernel<<<(M_ * C_ + 255) / 256, 256, 0, stream>>>(b2, lb, rb, pot);

    const size_t need = (size_t)W1T_ELEMS * sizeof(unsigned short);  // 1.18 MB
    if (ws_size >= need) {
        unsigned short* w1t = (unsigned short*)d_ws;
        dim3 pgrid(H_ / 32, D_ / 32);
        prep_w1_kernel<<<pgrid, 256, 0, stream>>>(W1, w1t);
        gemm_bf16_kernel<<<1536, 256, 0, stream>>>(hs, w1t, b1, W2, pot);
    } else {
        dim3 grid(H_ / 128, M_ / 128);
        gemm_relu_pot_kernel<<<grid, 256, 0, stream>>>(hs, W1, b1, W2, pot);
    }

    viterbi_kernel<<<B_, 64, 0, stream>>>(pot, chain, mask, decoded, seq, chainout);
}

// Round 4
// 276.354 us; speedup vs baseline: 2.3866x; 1.2548x over previous
//
#include <hip/hip_runtime.h>

// Problem constants
#define B_  64
#define S_  512
#define D_  768
#define H_  768
#define C_  5
#define M_  (B_ * S_)        // 32768 rows

typedef float f32x4 __attribute__((ext_vector_type(4)));
typedef short short8 __attribute__((ext_vector_type(8)));   // bf16x8 MFMA operand

#define W1T_ELEMS (D_ * H_)      // 589824  (bf16: 1.18 MB)
#define XBF_ELEMS (M_ * D_)      // 25165824 (bf16: 50.33 MB)

__device__ __forceinline__ unsigned short f2bf(float f) {
    unsigned int u = __float_as_uint(f);
    u += 0x7FFFu + ((u >> 16) & 1u);     // RNE
    return (unsigned short)(u >> 16);
}

// =========================================================================
// Kernel 1: init pot = b2 + boundaries (pot lives in d_out; poisoned each run)
// =========================================================================
__global__ __launch_bounds__(256) void init_pot_kernel(
    const float* __restrict__ b2, const float* __restrict__ lb,
    const float* __restrict__ rb, float* __restrict__ pot)
{
    const int idx = blockIdx.x * 256 + threadIdx.x;
    if (idx < M_ * C_) {
        const int c = idx % C_;
        const int t = (idx / C_) & (S_ - 1);
        float v = b2[c];
        if (t == 0)      v += lb[c];
        if (t == S_ - 1) v += rb[c];
        pot[idx] = v;
    }
}

// =========================================================================
// Kernel 2a: W1 [k][n] fp32 -> w1t [n][k] bf16 (LDS-tiled transpose)
// =========================================================================
__global__ __launch_bounds__(256) void prep_w1_kernel(
    const float* __restrict__ W1, unsigned short* __restrict__ w1t)
{
    __shared__ float t[32][33];
    const int bx = blockIdx.x;            // n tile (24)
    const int by = blockIdx.y;            // k tile (24)
    const int lx = threadIdx.x & 31, ly = threadIdx.x >> 5;   // 32 x 8
    #pragma unroll
    for (int j = 0; j < 4; ++j)
        t[ly + 8 * j][lx] = W1[(by * 32 + ly + 8 * j) * H_ + bx * 32 + lx];
    __syncthreads();
    #pragma unroll
    for (int j = 0; j < 4; ++j)
        w1t[(size_t)(bx * 32 + ly + 8 * j) * D_ + by * 32 + lx] = f2bf(t[lx][ly + 8 * j]);
}

// =========================================================================
// Kernel 2b: X fp32 -> bf16 (elementwise, memory-bound; hoists the cvt that
// dominated R3's K-loop: VALUBusy 30% vs MfmaUtil 9.5%)
// =========================================================================
__global__ __launch_bounds__(256) void prep_x_kernel(
    const float* __restrict__ X, unsigned short* __restrict__ xbf)
{
    const size_t i0 = ((size_t)blockIdx.x * 256 + threadIdx.x) * 8;
    const float4 a = *(const float4*)(X + i0);
    const float4 b = *(const float4*)(X + i0 + 4);
    union { unsigned short u[8]; uint4 v; } o;
    o.u[0] = f2bf(a.x); o.u[1] = f2bf(a.y); o.u[2] = f2bf(a.z); o.u[3] = f2bf(a.w);
    o.u[4] = f2bf(b.x); o.u[5] = f2bf(b.y); o.u[6] = f2bf(b.z); o.u[7] = f2bf(b.w);
    *(uint4*)(xbf + i0) = o.v;
}

// =========================================================================
// Kernel 2c: pure-bf16 MFMA GEMM (m97 structure). 128x128 tile, BK=32,
// global_load_lds width-16 staging, chunk-linear LDS layout (slot = 8*lane
// per 16-row group) -> fragment ds_read_b128 sweeps 1 KB contiguous: 0
// conflicts (verified R3). Epilogue: relu(h+b1)@W2 -> LDS -> 640 atomics.
// =========================================================================
__device__ __forceinline__ void gload16(const void* g, void* l) {
    __builtin_amdgcn_global_load_lds(
        (const __attribute__((address_space(1))) unsigned int*)g,
        (__attribute__((address_space(3))) unsigned int*)l, 16, 0, 0);
}

__global__ __launch_bounds__(256) void gemm_bf16x2_kernel(
    const unsigned short* __restrict__ xbf,   // [M_, D_] bf16
    const unsigned short* __restrict__ w1t,   // [H_, D_] bf16 (n-major)
    const float* __restrict__ b1,
    const float* __restrict__ W2,             // [H_, C_]
    float* __restrict__ pot)                  // [M_, C_] pre-initialized
{
    __shared__ __align__(16) unsigned short Asm[128 * 32];   // 8 KB
    __shared__ __align__(16) unsigned short Bsm[128 * 32];   // 8 KB
    __shared__ float pp[2][128][C_];                          // 5 KB

    const int tid  = threadIdx.x;
    const int lane = tid & 63, w = tid >> 6;
    const int wm   = w >> 1, wn = w & 1;
    const int i15  = lane & 15, quad = lane >> 4;

    // XCD swizzle: 6 n-blocks of an m-tile land on the same XCD (bid%8)
    const int bid = blockIdx.x;
    const int r8 = bid & 7, q8 = bid >> 3;
    const int nb = q8 % 6, mhi = q8 / 6;
    const int m0 = (mhi * 8 + r8) * 128;
    const int n0 = nb * 128;

    // staging: wave w owns A-groups {2w,2w+1} and B-groups {2w,2w+1}
    const unsigned short* gA[2];
    const unsigned short* gB[2];
    unsigned short* lA[2];
    unsigned short* lB[2];
    #pragma unroll
    for (int i = 0; i < 2; ++i) {
        const int g = 2 * w + i;
        gA[i] = xbf + (size_t)(m0 + g * 16 + i15) * D_ + quad * 8;
        lA[i] = &Asm[g * 512];
        gB[i] = w1t + (size_t)(n0 + g * 16 + i15) * D_ + quad * 8;
        lB[i] = &Bsm[g * 512];
    }

    f32x4 acc[4][4];
    #pragma unroll
    for (int mi = 0; mi < 4; ++mi)
        #pragma unroll
        for (int ni = 0; ni < 4; ++ni)
            acc[mi][ni] = (f32x4){0.f, 0.f, 0.f, 0.f};

    for (int kt = 0; kt < D_ / 32; ++kt) {
        __syncthreads();                      // prev iter's fragment reads done
        #pragma unroll
        for (int i = 0; i < 2; ++i) { gload16(gA[i], lA[i]); gA[i] += 32; }
        #pragma unroll
        for (int i = 0; i < 2; ++i) { gload16(gB[i], lB[i]); gB[i] += 32; }
        __syncthreads();                      // vmcnt(0) drain before barrier

        short8 af[4], bfr[4];
        #pragma unroll
        for (int mi = 0; mi < 4; ++mi)
            af[mi] = *(const short8*)&Asm[(wm * 4 + mi) * 512 + quad * 128 + i15 * 8];
        #pragma unroll
        for (int ni = 0; ni < 4; ++ni)
            bfr[ni] = *(const short8*)&Bsm[(wn * 4 + ni) * 512 + quad * 128 + i15 * 8];

        #pragma unroll
        for (int ni = 0; ni < 4; ++ni)
            #pragma unroll
            for (int mi = 0; mi < 4; ++mi)
                acc[mi][ni] = __builtin_amdgcn_mfma_f32_16x16x32_bf16(
                    af[mi], bfr[ni], acc[mi][ni], 0, 0, 0);
    }

    // ---- epilogue: relu(h+b1)@W2, wave-partial -> LDS -> block atomics ----
    float b1v[4], w2v[4][C_];
    #pragma unroll
    for (int ni = 0; ni < 4; ++ni) {
        const int col = n0 + wn * 64 + ni * 16 + i15;
        b1v[ni] = b1[col];
        #pragma unroll
        for (int cc = 0; cc < C_; ++cc) w2v[ni][cc] = W2[col * C_ + cc];
    }

    #pragma unroll
    for (int mi = 0; mi < 4; ++mi) {
        float ps[4][C_];
        #pragma unroll
        for (int r = 0; r < 4; ++r)
            #pragma unroll
            for (int cc = 0; cc < C_; ++cc) ps[r][cc] = 0.f;

        #pragma unroll
        for (int ni = 0; ni < 4; ++ni)
            #pragma unroll
            for (int r = 0; r < 4; ++r) {
                float h = acc[mi][ni][r] + b1v[ni];
                h = h > 0.f ? h : 0.f;
                #pragma unroll
                for (int cc = 0; cc < C_; ++cc)
                    ps[r][cc] = fmaf(h, w2v[ni][cc], ps[r][cc]);
            }

        #pragma unroll
        for (int off = 1; off < 16; off <<= 1)
            #pragma unroll
            for (int r = 0; r < 4; ++r)
                #pragma unroll
                for (int cc = 0; cc < C_; ++cc)
                    ps[r][cc] += __shfl_xor(ps[r][cc], off, 64);

        if (i15 == 0) {
            #pragma unroll
            for (int r = 0; r < 4; ++r) {
                const int row = wm * 64 + mi * 16 + quad * 4 + r;
                #pragma unroll
                for (int cc = 0; cc < C_; ++cc)
                    pp[wn][row][cc] = ps[r][cc];
            }
        }
    }
    __syncthreads();

    for (int idx = tid; idx < 128 * C_; idx += 256) {
        const int row = idx / C_, cc = idx % C_;
        atomicAdd(&pot[(size_t)(m0 + row) * C_ + cc],
                  pp[0][row][cc] + pp[1][row][cc]);
    }
}

// =========================================================================
// Mid fallback (R3 kernel, proven 162 us): bf16 B from ws, fp32 A in-loop cvt
// =========================================================================
__global__ __launch_bounds__(256) void gemm_bf16_kernel(
    const float* __restrict__ X,
    const unsigned short* __restrict__ w1t,
    const float* __restrict__ b1,
    const float* __restrict__ W2,
    float* __restrict__ pot)
{
    __shared__ __align__(16) float          Asm[128 * 32];
    __shared__ __align__(16) unsigned short Bsm[128 * 32];
    __shared__ float pp[2][128][C_];

    const int tid  = threadIdx.x;
    const int lane = tid & 63, w = tid >> 6;
    const int wm   = w >> 1, wn = w & 1;
    const int i15  = lane & 15, quad = lane >> 4;

    const int bid = blockIdx.x;
    const int r8 = bid & 7, q8 = bid >> 3;
    const int nb = q8 % 6, mhi = q8 / 6;
    const int m0 = (mhi * 8 + r8) * 128;
    const int n0 = nb * 128;

    const float* gA[4];
    float* lA[4];
    const unsigned short* gB[2];
    unsigned short* lB[2];
    #pragma unroll
    for (int i = 0; i < 4; ++i) {
        const int a = 4 * w + i, g = a >> 1, h = a & 1;
        gA[i] = X + (size_t)(m0 + g * 16 + i15) * D_ + (4 * h + quad) * 4;
        lA[i] = &Asm[g * 512 + h * 256];
    }
    #pragma unroll
    for (int i = 0; i < 2; ++i) {
        const int b = 2 * w + i;
        gB[i] = w1t + (size_t)(n0 + b * 16 + i15) * D_ + quad * 8;
        lB[i] = &Bsm[b * 512];
    }

    f32x4 acc[4][4];
    #pragma unroll
    for (int mi = 0; mi < 4; ++mi)
        #pragma unroll
        for (int ni = 0; ni < 4; ++ni)
            acc[mi][ni] = (f32x4){0.f, 0.f, 0.f, 0.f};

    for (int kt = 0; kt < D_ / 32; ++kt) {
        __syncthreads();
        #pragma unroll
        for (int i = 0; i < 4; ++i) { gload16(gA[i], lA[i]); gA[i] += 32; }
        #pragma unroll
        for (int i = 0; i < 2; ++i) { gload16(gB[i], lB[i]); gB[i] += 32; }
        __syncthreads();

        short8 af[4];
        #pragma unroll
        for (int mi = 0; mi < 4; ++mi) {
            const int row = wm * 64 + mi * 16 + i15;
            const int base = (row >> 4) * 512 + (row & 15) * 4 + quad * 128;
            const f32x4 lo = *(const f32x4*)&Asm[base];
            const f32x4 hi = *(const f32x4*)&Asm[base + 64];
            float f[8];
            *(f32x4*)&f[0] = lo; *(f32x4*)&f[4] = hi;
            union { short8 s; unsigned short u[8]; } cv;
            #pragma unroll
            for (int j = 0; j < 8; ++j) cv.u[j] = f2bf(f[j]);
            af[mi] = cv.s;
        }
        short8 bfr[4];
        #pragma unroll
        for (int ni = 0; ni < 4; ++ni) {
            const int row = wn * 64 + ni * 16 + i15;
            bfr[ni] = *(const short8*)&Bsm[(row >> 4) * 512 + quad * 128 + (row & 15) * 8];
        }
        #pragma unroll
        for (int ni = 0; ni < 4; ++ni)
            #pragma unroll
            for (int mi = 0; mi < 4; ++mi)
                acc[mi][ni] = __builtin_amdgcn_mfma_f32_16x16x32_bf16(
                    af[mi], bfr[ni], acc[mi][ni], 0, 0, 0);
    }

    float b1v[4], w2v[4][C_];
    #pragma unroll
    for (int ni = 0; ni < 4; ++ni) {
        const int col = n0 + wn * 64 + ni * 16 + i15;
        b1v[ni] = b1[col];
        #pragma unroll
        for (int cc = 0; cc < C_; ++cc) w2v[ni][cc] = W2[col * C_ + cc];
    }

    #pragma unroll
    for (int mi = 0; mi < 4; ++mi) {
        float ps[4][C_];
        #pragma unroll
        for (int r = 0; r < 4; ++r)
            #pragma unroll
            for (int cc = 0; cc < C_; ++cc) ps[r][cc] = 0.f;

        #pragma unroll
        for (int ni = 0; ni < 4; ++ni)
            #pragma unroll
            for (int r = 0; r < 4; ++r) {
                float h = acc[mi][ni][r] + b1v[ni];
                h = h > 0.f ? h : 0.f;
                #pragma unroll
                for (int cc = 0; cc < C_; ++cc)
                    ps[r][cc] = fmaf(h, w2v[ni][cc], ps[r][cc]);
            }

        #pragma unroll
        for (int off = 1; off < 16; off <<= 1)
            #pragma unroll
            for (int r = 0; r < 4; ++r)
                #pragma unroll
                for (int cc = 0; cc < C_; ++cc)
                    ps[r][cc] += __shfl_xor(ps[r][cc], off, 64);

        if (i15 == 0) {
            #pragma unroll
            for (int r = 0; r < 4; ++r) {
                const int row = wm * 64 + mi * 16 + quad * 4 + r;
                #pragma unroll
                for (int cc = 0; cc < C_; ++cc)
                    pp[wn][row][cc] = ps[r][cc];
            }
        }
    }
    __syncthreads();

    for (int idx = tid; idx < 128 * C_; idx += 256) {
        const int row = idx / C_, cc = idx % C_;
        atomicAdd(&pot[(size_t)(m0 + row) * C_ + cc],
                  pp[0][row][cc] + pp[1][row][cc]);
    }
}

// =========================================================================
// Last-resort fp32 GEMM (R1 kernel) if ws < 1.18 MB
// =========================================================================
#define FBK 8
#define FLDS 132
__global__ __launch_bounds__(256) void gemm_relu_pot_kernel(
    const float* __restrict__ X, const float* __restrict__ W1,
    const float* __restrict__ b1, const float* __restrict__ W2,
    float* __restrict__ pot)
{
    __shared__ float As[FBK * FLDS];
    __shared__ float Bs[FBK * FLDS];
    __shared__ float w2s[128][C_];

    const int tid = threadIdx.x;
    const int tx = tid & 15, ty = tid >> 4;
    const int m0 = blockIdx.y * 128, n0 = blockIdx.x * 128;

    for (int idx = tid; idx < 128 * C_; idx += 256)
        w2s[idx / C_][idx % C_] = W2[(n0 + idx / C_) * C_ + idx % C_];

    float acc[2][2][4][4];
    #pragma unroll
    for (int a = 0; a < 2; ++a)
        #pragma unroll
        for (int b = 0; b < 2; ++b)
            #pragma unroll
            for (int i = 0; i < 4; ++i)
                #pragma unroll
                for (int j = 0; j < 4; ++j) acc[a][b][i][j] = 0.f;

    const int arow = tid >> 1, aq = tid & 1;
    const int brow = tid >> 5, bq = tid & 31;
    const float* Aptr = X + (m0 + arow) * D_ + aq * 4;
    const float* Bptr = W1 + brow * H_ + n0 + bq * 4;

    for (int kt = 0; kt < D_; kt += FBK) {
        const float4 avv = *(const float4*)Aptr;
        const float4 bvv = *(const float4*)Bptr;
        __syncthreads();
        As[(aq * 4 + 0) * FLDS + arow] = avv.x;
        As[(aq * 4 + 1) * FLDS + arow] = avv.y;
        As[(aq * 4 + 2) * FLDS + arow] = avv.z;
        As[(aq * 4 + 3) * FLDS + arow] = avv.w;
        *(float4*)&Bs[brow * FLDS + bq * 4] = bvv;
        __syncthreads();
        #pragma unroll
        for (int k = 0; k < FBK; ++k) {
            const float4 a0 = *(const float4*)&As[k * FLDS + (ty << 2)];
            const float4 a1 = *(const float4*)&As[k * FLDS + 64 + (ty << 2)];
            const float4 b0 = *(const float4*)&Bs[k * FLDS + (tx << 2)];
            const float4 b1r = *(const float4*)&Bs[k * FLDS + 64 + (tx << 2)];
            const float ar[2][4] = {{a0.x,a0.y,a0.z,a0.w},{a1.x,a1.y,a1.z,a1.w}};
            const float br[2][4] = {{b0.x,b0.y,b0.z,b0.w},{b1r.x,b1r.y,b1r.z,b1r.w}};
            #pragma unroll
            for (int ri = 0; ri < 2; ++ri)
                #pragma unroll
                for (int i = 0; i < 4; ++i)
                    #pragma unroll
                    for (int rj = 0; rj < 2; ++rj)
                        #pragma unroll
                        for (int j = 0; j < 4; ++j)
                            acc[ri][rj][i][j] = fmaf(ar[ri][i], br[rj][j], acc[ri][rj][i][j]);
        }
        Aptr += FBK;
        Bptr += FBK * H_;
    }

    float ps[2][4][C_];
    #pragma unroll
    for (int ri = 0; ri < 2; ++ri)
        #pragma unroll
        for (int i = 0; i < 4; ++i)
            #pragma unroll
            for (int cc = 0; cc < C_; ++cc) ps[ri][i][cc] = 0.f;

    #pragma unroll
    for (int rj = 0; rj < 2; ++rj)
        #pragma unroll
        for (int j = 0; j < 4; ++j) {
            const int nl = rj * 64 + (tx << 2) + j;
            const float bj = b1[n0 + nl];
            float w2c[C_];
            #pragma unroll
            for (int cc = 0; cc < C_; ++cc) w2c[cc] = w2s[nl][cc];
            #pragma unroll
            for (int ri = 0; ri < 2; ++ri)
                #pragma unroll
                for (int i = 0; i < 4; ++i) {
                    float h = acc[ri][rj][i][j] + bj;
                    h = h > 0.f ? h : 0.f;
                    #pragma unroll
                    for (int cc = 0; cc < C_; ++cc)
                        ps[ri][i][cc] = fmaf(h, w2c[cc], ps[ri][i][cc]);
                }
        }

    #pragma unroll
    for (int off = 1; off < 16; off <<= 1)
        #pragma unroll
        for (int ri = 0; ri < 2; ++ri)
            #pragma unroll
            for (int i = 0; i < 4; ++i)
                #pragma unroll
                for (int cc = 0; cc < C_; ++cc)
                    ps[ri][i][cc] += __shfl_xor(ps[ri][i][cc], off, 64);

    if (tx == 0)
        #pragma unroll
        for (int ri = 0; ri < 2; ++ri)
            #pragma unroll
            for (int i = 0; i < 4; ++i) {
                const int m = m0 + ri * 64 + (ty << 2) + i;
                #pragma unroll
                for (int cc = 0; cc < C_; ++cc)
                    atomicAdd(&pot[m * C_ + cc], ps[ri][i][cc]);
            }
}

// =========================================================================
// Kernel 3: Viterbi via max-plus associative scan.
//   Phase 1: lane l composes its 8 step-matrices M_t (t=8l+1..8l+8) -> S_l
//   Phase 2: Hillis-Steele inclusive matrix scan over 64 lanes (6 rounds),
//            exclusive shift -> boundary alpha_{8l} per lane
//   Phase 3: per-lane 8-step replay -> packed 3-bit backpointers
//   Backtrace: segment-composition (R3-verified) + per-lane replay.
// =========================================================================
__global__ __launch_bounds__(64) void viterbi_kernel(
    const float* __restrict__ pot, const float* __restrict__ trans,
    const int* __restrict__ mask, float* __restrict__ decoded,
    float* __restrict__ seqlen, float* __restrict__ chain_out)
{
    const int b = blockIdx.x;
    const int lane = threadIdx.x;

    __shared__ float pl[S_ * C_];
    __shared__ unsigned int bpk[S_];
    __shared__ unsigned int gseg[64];
    __shared__ int bt[64];
    __shared__ int dec_s[S_];
    __shared__ int s_last;

    const float* pb = pot + b * (S_ * C_);
    for (int i = lane; i < S_ * C_; i += 64) pl[i] = pb[i];

    int mcnt = 0;
    const int* mb = mask + b * S_;
    for (int i = lane; i < S_; i += 64) mcnt += (mb[i] != 0) ? 1 : 0;
    #pragma unroll
    for (int off = 32; off >= 1; off >>= 1) mcnt += __shfl_xor(mcnt, off, 64);

    if (b == 0 && lane < C_ * C_) chain_out[lane] = trans[lane];

    float tr[C_][C_];
    #pragma unroll
    for (int p = 0; p < C_; ++p)
        #pragma unroll
        for (int c = 0; c < C_; ++c) tr[p][c] = trans[p * C_ + c];

    __syncthreads();

    const float NEG = -1.0e30f;

    // Phase 1: segment matrix G (G[c][p]: best path weight tag_{t0}=p -> tag_{t1}=c)
    float G[C_][C_];
    #pragma unroll
    for (int c = 0; c < C_; ++c)
        #pragma unroll
        for (int p = 0; p < C_; ++p) G[c][p] = (c == p) ? 0.f : NEG;

    for (int j = 1; j <= 8; ++j) {
        const int t = 8 * lane + j;
        if (t < S_) {
            float ng[C_][C_];
            #pragma unroll
            for (int c = 0; c < C_; ++c) {
                const float pc = pl[t * C_ + c];
                #pragma unroll
                for (int p = 0; p < C_; ++p) {
                    float m = tr[0][c] + G[0][p];
                    #pragma unroll
                    for (int q = 1; q < C_; ++q)
                        m = fmaxf(m, tr[q][c] + G[q][p]);
                    ng[c][p] = m + pc;
                }
            }
            #pragma unroll
            for (int c = 0; c < C_; ++c)
                #pragma unroll
                for (int p = 0; p < C_; ++p) G[c][p] = ng[c][p];
        }
    }

    // Phase 2: inclusive matrix scan (mine applied after fetched-earlier)
    #pragma unroll
    for (int d = 1; d < 64; d <<= 1) {
        float Q[C_][C_];
        #pragma unroll
        for (int q = 0; q < C_; ++q)
            #pragma unroll
            for (int p = 0; p < C_; ++p) Q[q][p] = __shfl_up(G[q][p], d, 64);
        if (lane >= d) {
            float ng[C_][C_];
            #pragma unroll
            for (int c = 0; c < C_; ++c)
                #pragma unroll
                for (int p = 0; p < C_; ++p) {
                    float m = G[c][0] + Q[0][p];
                    #pragma unroll
                    for (int q = 1; q < C_; ++q)
                        m = fmaxf(m, G[c][q] + Q[q][p]);
                    ng[c][p] = m;
                }
            #pragma unroll
            for (int c = 0; c < C_; ++c)
                #pragma unroll
                for (int p = 0; p < C_; ++p) G[c][p] = ng[c][p];
        }
    }

    // exclusive shift -> E = scan result of lane-1; alpha_{8*lane} = E (x) alpha_0
    float a[C_];
    {
        float E[C_][C_];
        #pragma unroll
        for (int c = 0; c < C_; ++c)
            #pragma unroll
            for (int p = 0; p < C_; ++p) E[c][p] = __shfl_up(G[c][p], 1, 64);
        float a0[C_];
        #pragma unroll
        for (int c = 0; c < C_; ++c) a0[c] = pl[c];
        if (lane == 0) {
            #pragma unroll
            for (int c = 0; c < C_; ++c) a[c] = a0[c];
        } else {
            #pragma unroll
            for (int c = 0; c < C_; ++c) {
                float m = E[c][0] + a0[0];
                #pragma unroll
                for (int q = 1; q < C_; ++q) m = fmaxf(m, E[c][q] + a0[q]);
                a[c] = m;
            }
        }
    }

    // Phase 3: replay 8 steps, emit packed backpointers (first-max tiebreak)
    for (int j = 1; j <= 8; ++j) {
        const int t = 8 * lane + j;
        if (t < S_) {
            unsigned int mpack = 0;
            float na[C_];
            #pragma unroll
            for (int c = 0; c < C_; ++c) {
                float best = a[0] + tr[0][c];
                int arg = 0;
                #pragma unroll
                for (int p = 1; p < C_; ++p) {
                    const float s = a[p] + tr[p][c];
                    if (s > best) { best = s; arg = p; }
                }
                mpack |= (unsigned int)arg << (3 * c);
                na[c] = best + pl[t * C_ + c];
            }
            bpk[t] = mpack;
            #pragma unroll
            for (int c = 0; c < C_; ++c) a[c] = na[c];
        }
    }

    // final alpha_{511} lives in lane 63; first-max argmax
    if (lane == 63) {
        float best = a[0];
        int arg = 0;
        #pragma unroll
        for (int p = 1; p < C_; ++p)
            if (a[p] > best) { best = a[p]; arg = p; }
        s_last = arg;
    }
    if (lane == 0) bpk[0] = 0;
    __syncthreads();

    const int last = s_last;

    // backtrace: segment composition (lane l covers t in [8l, 8l+7])
    unsigned int g = 0u | (1u << 3) | (2u << 6) | (3u << 9) | (4u << 12);
    #pragma unroll
    for (int j = 7; j >= 0; --j) {
        const int t = 8 * lane + j;
        if (t >= 1) {
            const unsigned int m = bpk[t];
            unsigned int ng = 0;
            #pragma unroll
            for (int x = 0; x < C_; ++x) {
                const unsigned int gx = (g >> (3 * x)) & 7u;
                ng |= ((m >> (3 * gx)) & 7u) << (3 * x);
            }
            g = ng;
        }
    }
    gseg[lane] = g;
    __syncthreads();

    if (lane == 0) {
        int cur = last;
        for (int l = 63; l >= 0; --l) {
            bt[l] = cur;                       // tag_{8l+7}
            cur = (int)((gseg[l] >> (3 * cur)) & 7u);
        }
        seqlen[b] = (float)mcnt;
    }
    __syncthreads();

    {
        int tag = bt[lane];
        const int t0 = 8 * lane;
        dec_s[t0 + 7] = tag;
        #pragma unroll
        for (int t = t0 + 7; t >= t0 + 1; --t) {
            tag = (int)((bpk[t] >> (3 * tag)) & 7u);
            dec_s[t - 1] = tag;
        }
    }
    __syncthreads();

    float* db = decoded + b * S_;
    for (int i = lane; i < S_; i += 64) db[i] = (float)dec_s[i];
}

// =========================================================================
extern "C" void kernel_launch(void* const* d_in, const int* in_sizes, int n_in,
                              void* d_out, int out_size, void* d_ws, size_t ws_size,
                              hipStream_t stream) {
    const float* hs    = (const float*)d_in[0];
    const int*   mask  = (const int*)  d_in[1];
    const float* W1    = (const float*)d_in[2];
    const float* b1    = (const float*)d_in[3];
    const float* W2    = (const float*)d_in[4];
    const float* b2    = (const float*)d_in[5];
    const float* chain = (const float*)d_in[6];
    const float* lb    = (const float*)d_in[7];
    const float* rb    = (const float*)d_in[8];

    float* out      = (float*)d_out;
    float* decoded  = out;
    float* pot      = out + M_;
    float* seq      = out + M_ + M_ * C_;
    float* chainout = seq + B_;

    init_pot_kernel<<<(M_ * C_ + 255) / 256, 256, 0, stream>>>(b2, lb, rb, pot);

    const size_t need_w1 = (size_t)W1T_ELEMS * sizeof(unsigned short);      // 1.18 MB
    const size_t need_all = need_w1 + (size_t)XBF_ELEMS * sizeof(unsigned short); // 51.5 MB

    if (ws_size >= need_all) {
        unsigned short* w1t = (unsigned short*)d_ws;
        unsigned short* xbf = w1t + W1T_ELEMS;
        dim3 pgrid(H_ / 32, D_ / 32);
        prep_w1_kernel<<<pgrid, 256, 0, stream>>>(W1, w1t);
        prep_x_kernel<<<XBF_ELEMS / (256 * 8), 256, 0, stream>>>(hs, xbf);
        gemm_bf16x2_kernel<<<1536, 256, 0, stream>>>(xbf, w1t, b1, W2, pot);
    } else if (ws_size >= need_w1) {
        unsigned short* w1t = (unsigned short*)d_ws;
        dim3 pgrid(H_ / 32, D_ / 32);
        prep_w1_kernel<<<pgrid, 256, 0, stream>>>(W1, w1t);
        gemm_bf16_kernel<<<1536, 256, 0, stream>>>(hs, w1t, b1, W2, pot);
    } else {
        dim3 grid(H_ / 128, M_ / 128);
        gemm_relu_pot_kernel<<<grid, 256, 0, stream>>>(hs, W1, b1, W2, pot);
    }

    viterbi_kernel<<<B_, 64, 0, stream>>>(pot, chain, mask, decoded, seq, chainout);
}